// Round 11
// baseline (196.934 us; speedup 1.0000x reference)
//
#include <hip/hip_runtime.h>
#include <hip/hip_bf16.h>

#define S_LEN 2048
#define D_DIM 64
#define NBH   32
#define NE    (NBH * S_LEN * D_DIM)   // 4,194,304 elements per tensor

typedef __attribute__((ext_vector_type(8))) short bf16x8;
typedef __attribute__((ext_vector_type(2))) unsigned u32x2;
typedef __attribute__((ext_vector_type(4))) unsigned u32x4;
typedef __attribute__((ext_vector_type(4))) float f32x4;

__device__ __forceinline__ f32x4 mfma16(bf16x8 a, bf16x8 b, f32x4 c) {
  return __builtin_amdgcn_mfma_f32_16x16x32_bf16(a, b, c, 0, 0, 0);
}

__device__ __forceinline__ void gload16(const void* g, void* l) {
  __builtin_amdgcn_global_load_lds(
      (const __attribute__((address_space(1))) unsigned*)g,
      (__attribute__((address_space(3))) unsigned*)l, 16, 0, 0);
}

// packed bf16 convert (RNE): low16 = bf16(a), high16 = bf16(b)
__device__ __forceinline__ unsigned cvtpk(float a, float b) {
  unsigned r;
  asm("v_cvt_pk_bf16_f32 %0, %1, %2" : "=v"(r) : "v"(a), "v"(b));
  return r;
}
// hi/lo split of a pair via cvt_pk: returns {H, L} packed words
__device__ __forceinline__ u32x2 split2(float a, float b) {
  u32x2 r;
  r.x = cvtpk(a, b);
  const float fa = __builtin_bit_cast(float, r.x << 16);
  const float fb = __builtin_bit_cast(float, r.x & 0xffff0000u);
  r.y = cvtpk(a - fa, b - fb);
  return r;
}

// ---------- fused pre-pass: K -> Kh/Kl (same layout); V -> Vh/Vl transposed [bh][d][s]
__global__ __launch_bounds__(256) void prepass(const float* __restrict__ K,
                                               const float* __restrict__ V,
                                               unsigned short* __restrict__ Kh,
                                               unsigned short* __restrict__ Kl,
                                               unsigned short* __restrict__ Vh,
                                               unsigned short* __restrict__ Vl) {
  __shared__ float t[64][65];
  const int tid = threadIdx.x;
  if (blockIdx.x < 2048) {             // K convert: 8 floats / thread
    const int i = ((int)blockIdx.x * 256 + tid) * 8;
    float4 v0 = *(const float4*)(K + i);
    float4 v1 = *(const float4*)(K + i + 4);
    u32x4 H, L;
    u32x2 s;
    s = split2(v0.x, v0.y); H[0] = s.x; L[0] = s.y;
    s = split2(v0.z, v0.w); H[1] = s.x; L[1] = s.y;
    s = split2(v1.x, v1.y); H[2] = s.x; L[2] = s.y;
    s = split2(v1.z, v1.w); H[3] = s.x; L[3] = s.y;
    *(u32x4*)(Kh + i) = H;
    *(u32x4*)(Kl + i) = L;
  } else {                             // V transpose + convert
    const int bid = (int)blockIdx.x - 2048;
    const int bh  = bid >> 5;
    const int kv0 = (bid & 31) << 6;
#pragma unroll
    for (int pp = 0; pp < 4; ++pp) {
      const int r  = (tid >> 4) + pp * 16;
      const int c4 = (tid & 15) << 2;
      float4 v = *(const float4*)(V + ((size_t)bh * S_LEN + kv0 + r) * D_DIM + c4);
      t[r][c4] = v.x; t[r][c4 + 1] = v.y; t[r][c4 + 2] = v.z; t[r][c4 + 3] = v.w;
    }
    __syncthreads();
    const int d  = tid >> 2;
    const int k0 = (tid & 3) << 4;
    u32x4 H0, L0, H1, L1;
#pragma unroll
    for (int jj = 0; jj < 4; ++jj) {
      u32x2 s = split2(t[k0 + 2 * jj][d], t[k0 + 2 * jj + 1][d]);
      H0[jj] = s.x; L0[jj] = s.y;
    }
#pragma unroll
    for (int jj = 0; jj < 4; ++jj) {
      u32x2 s = split2(t[k0 + 8 + 2 * jj][d], t[k0 + 9 + 2 * jj][d]);
      H1[jj] = s.x; L1[jj] = s.y;
    }
    const size_t ob = ((size_t)bh * D_DIM + d) * S_LEN + kv0 + k0;
    *(u32x4*)(Vh + ob)     = H0;
    *(u32x4*)(Vh + ob + 8) = H1;
    *(u32x4*)(Vl + ob)     = L0;
    *(u32x4*)(Vl + ob + 8) = L1;
  }
}

// ---------- main: swapped-QK flash attention, prefetch dbuf, KBLK=32, P in registers
__global__ __launch_bounds__(256) void attn_main(const float* __restrict__ Q,
                                                 const unsigned short* __restrict__ Kh,
                                                 const unsigned short* __restrict__ Kl,
                                                 const unsigned short* __restrict__ Vh,
                                                 const unsigned short* __restrict__ Vl,
                                                 float* __restrict__ Out) {
  __shared__ __align__(16) char smem[32768];               // 32KB -> 5 blocks/CU
  unsigned short* sKh = (unsigned short*)smem;             // [2][32 kv][64 d] 8KB
  unsigned short* sKl = (unsigned short*)(smem + 8192);
  unsigned short* sVh = (unsigned short*)(smem + 16384);   // [2][64 d][32 kv] 8KB
  unsigned short* sVl = (unsigned short*)(smem + 24576);

  const int tid   = threadIdx.x;
  const int bh    = blockIdx.x & 31;          // same bh -> same XCD (32 % 8 == 0)
  const int qt    = 31 - (blockIdx.x >> 5);   // longest blocks first
  const int qbase = qt << 6;
  const int wave  = tid >> 6;
  const int lane  = tid & 63;
  const int c     = lane & 15;                // lane's q-row offset
  const int g     = lane >> 4;
  const int qw    = qbase + (wave << 4);

  const size_t bhO = (size_t)bh * (S_LEN * D_DIM);

  // Q as B-fragment: col = c = q-row, k = 8g+e = d. scale*log2e folded pre-split.
  const float SC = 0.125f * 1.44269504088896340736f;
  bf16x8 qh[2], ql[2];
#pragma unroll
  for (int ch = 0; ch < 2; ++ch) {
    const float* src = Q + bhO + (size_t)(qw + c) * D_DIM + ch * 32 + g * 8;
    float4 v0 = *(const float4*)src;
    float4 v1 = *(const float4*)(src + 4);
    float a[8] = {v0.x, v0.y, v0.z, v0.w, v1.x, v1.y, v1.z, v1.w};
    u32x4 H, L;
    u32x2 s;
    s = split2(a[0] * SC, a[1] * SC); H[0] = s.x; L[0] = s.y;
    s = split2(a[2] * SC, a[3] * SC); H[1] = s.x; L[1] = s.y;
    s = split2(a[4] * SC, a[5] * SC); H[2] = s.x; L[2] = s.y;
    s = split2(a[6] * SC, a[7] * SC); H[3] = s.x; L[3] = s.y;
    qh[ch] = __builtin_bit_cast(bf16x8, H);
    ql[ch] = __builtin_bit_cast(bf16x8, L);
  }

  f32x4 acc[4] = {{0.f,0.f,0.f,0.f},{0.f,0.f,0.f,0.f},{0.f,0.f,0.f,0.f},{0.f,0.f,0.f,0.f}};
  float m_r = -3.0e38f, l_r = 0.f;            // lane owns q-row qw+c

  const unsigned short* gKh = Kh + bhO;
  const unsigned short* gKl = Kl + bhO;
  const unsigned short* gVh = Vh + bhO;
  const unsigned short* gVl = Vl + bhO;

  const int rs   = tid >> 3;                         // K stage row (kv)
  const int kswz = ((tid & 7) ^ (rs & 7)) << 3;      // K source XOR (128B rows)
  const int vrow = tid >> 2;                         // V stage row (d)
  const int vcol = (((tid & 3) ^ ((tid >> 3) & 3)) << 3);  // V source XOR (64B rows)

  // bpermute addrs for P gather (loop-invariant):
  // target word w pulls from lane c + 32*(g&1) + 16*(w>>1)
  const int bpa0 = (((lane & 15) + ((lane & 16) << 1)) << 2);
  const int bpa1 = bpa0 + 64;

  const int nIter = (qbase >> 5) + 2;

#define STAGE(itx, buf)                                                        \
  do {                                                                         \
    const int kv_ = (itx) << 5;                                                \
    gload16(gKh + (size_t)(kv_ + rs) * D_DIM + kswz,                           \
            sKh + ((buf) << 11) + (wave << 9));                                \
    gload16(gKl + (size_t)(kv_ + rs) * D_DIM + kswz,                           \
            sKl + ((buf) << 11) + (wave << 9));                                \
    gload16(gVh + (size_t)vrow * S_LEN + kv_ + vcol,                           \
            sVh + ((buf) << 11) + (wave << 9));                                \
    gload16(gVl + (size_t)vrow * S_LEN + kv_ + vcol,                           \
            sVl + ((buf) << 11) + (wave << 9));                                \
  } while (0)

  STAGE(0, 0);
  __syncthreads();
  int cur = 0;

  for (int it = 0; it < nIter; ++it) {
    if (it + 1 < nIter) STAGE(it + 1, cur ^ 1);   // prefetch: drains at END barrier
    const int kv0 = it << 5;

    if (kv0 <= qw + 15) {
      const int cb = cur << 11;
      // ---- QK^T swapped: S^T = mfma(A=K, B=Q). D: col=c=q, row=4g+r=kv-in-tile.
      f32x4 sj[2];
#pragma unroll
      for (int j = 0; j < 2; ++j) {
        const int row = (j << 4) + c;
        bf16x8 kfh[2], kfl[2];
#pragma unroll
        for (int ch = 0; ch < 2; ++ch) {
          const int p = ((ch << 2) + g) ^ (c & 7);
          kfh[ch] = *(const bf16x8*)&sKh[cb + (row << 6) + (p << 3)];
          kfl[ch] = *(const bf16x8*)&sKl[cb + (row << 6) + (p << 3)];
        }
        f32x4 sa = {0.f, 0.f, 0.f, 0.f};
        sa = mfma16(kfh[0], qh[0], sa);
        sa = mfma16(kfh[1], qh[1], sa);
        sa = mfma16(kfh[0], ql[0], sa);
        sa = mfma16(kfh[1], ql[1], sa);
        sa = mfma16(kfl[0], qh[0], sa);
        sa = mfma16(kfl[1], qh[1], sa);
        sj[j] = sa;
      }
      // causal mask: kv = kv0 + 16j + 4g + r vs q = qw + c
      if (kv0 + 31 > qw) {
#pragma unroll
        for (int j = 0; j < 2; ++j) {
          const int kvb = kv0 + (j << 4) + (g << 2);
#pragma unroll
          for (int r = 0; r < 4; ++r) {
            if (kvb + r > qw + c) sj[j][r] = -3.0e38f;
          }
        }
      }
      // ---- online softmax (lane-owned rows); defer-max: skip rescale if growth <= 8
      float pm = fmaxf(fmaxf(fmaxf(sj[0][0], sj[0][1]), fmaxf(sj[0][2], sj[0][3])),
                       fmaxf(fmaxf(sj[1][0], sj[1][1]), fmaxf(sj[1][2], sj[1][3])));
      pm = fmaxf(pm, __shfl_xor(pm, 16));
      pm = fmaxf(pm, __shfl_xor(pm, 32));
      if (!__all(pm <= m_r + 8.0f)) {       // p bounded by 2^8; scale cancels in l
        const float mn  = fmaxf(m_r, pm);
        const float fac = exp2f(m_r - mn);
        m_r = mn;
        l_r *= fac;
#pragma unroll
        for (int dt = 0; dt < 4; ++dt) acc[dt] *= fac;
      }
      float p[2][4];
      float ps = 0.f;
#pragma unroll
      for (int j = 0; j < 2; ++j)
#pragma unroll
        for (int r = 0; r < 4; ++r) {
          p[j][r] = exp2f(sj[j][r] - m_r);
          ps += p[j][r];
        }
      ps += __shfl_xor(ps, 16);
      ps += __shfl_xor(ps, 32);
      l_r += ps;

      // ---- pack P hi/lo into words W[j][k] (hi) / X[j][k] (lo)
      int Wj[2][2], Xj[2][2];
#pragma unroll
      for (int j = 0; j < 2; ++j) {
        u32x2 s0 = split2(p[j][0], p[j][1]);
        u32x2 s1 = split2(p[j][2], p[j][3]);
        Wj[j][0] = (int)s0.x; Xj[j][0] = (int)s0.y;
        Wj[j][1] = (int)s1.x; Xj[j][1] = (int)s1.y;
      }
      // ---- in-register transpose to PV B-frag via ds_bpermute:
      // word w <- lane c+32*(g&1)+16*(w>>1), register W[g>>1][w&1]
      const bool lowj = (lane < 32);      // g>>1 == 0
      u32x4 hw, lw;
#pragma unroll
      for (int w = 0; w < 4; ++w) {
        const int addr = (w < 2) ? bpa0 : bpa1;
        const int h0 = __builtin_amdgcn_ds_bpermute(addr, Wj[0][w & 1]);
        const int h1 = __builtin_amdgcn_ds_bpermute(addr, Wj[1][w & 1]);
        hw[w] = (unsigned)(lowj ? h0 : h1);
        const int l0 = __builtin_amdgcn_ds_bpermute(addr, Xj[0][w & 1]);
        const int l1 = __builtin_amdgcn_ds_bpermute(addr, Xj[1][w & 1]);
        lw[w] = (unsigned)(lowj ? l0 : l1);
      }
      const bf16x8 pbh = __builtin_bit_cast(bf16x8, hw);
      const bf16x8 pbl = __builtin_bit_cast(bf16x8, lw);

      // ---- PV: O^T = mfma(A=V^T, B=P^T); V slot swizzle ((c>>1)&3)
#pragma unroll
      for (int dt = 0; dt < 4; ++dt) {
        const int vb = cb + (((dt << 4) + c) << 5) + ((g ^ ((c >> 1) & 3)) << 3);
        const bf16x8 vfh = *(const bf16x8*)&sVh[vb];
        const bf16x8 vfl = *(const bf16x8*)&sVl[vb];
        acc[dt] = mfma16(vfh, pbh, acc[dt]);
        acc[dt] = mfma16(vfl, pbh, acc[dt]);
        acc[dt] = mfma16(vfh, pbl, acc[dt]);
      }
    }
    __syncthreads();   // drains prefetch (vmcnt) + guards buffer swap
    cur ^= 1;
  }

  // ---- epilogue: O^T in regs -> LDS bounce (conflict-free float4) -> global
  const float inv = 1.0f / l_r;
  float (*ob)[68] = (float(*)[68])smem;       // 64x68 f32 = 17408 B (fits 32KB)
#pragma unroll
  for (int dt = 0; dt < 4; ++dt) {
    f32x4 o = acc[dt] * inv;
    *(f32x4*)&ob[(wave << 4) + c][(dt << 4) + (g << 2)] = o;
  }
  __syncthreads();
#pragma unroll
  for (int v = 0; v < 4; ++v) {
    const int row = (tid >> 4) + (v << 4);
    const int dc  = (tid & 15) << 2;
    float4 val = *(const float4*)&ob[row][dc];
    *(float4*)(Out + bhO + (size_t)(qbase + row) * D_DIM + dc) = val;
  }
}

extern "C" void kernel_launch(void* const* d_in, const int* in_sizes, int n_in,
                              void* d_out, int out_size, void* d_ws, size_t ws_size,
                              hipStream_t stream) {
  const float* Q = (const float*)d_in[0];
  const float* K = (const float*)d_in[1];
  const float* V = (const float*)d_in[2];
  // d_in[3] = mask: static causal tril, implemented analytically.

  unsigned short* Kh = (unsigned short*)d_ws;          // 4 bf16 tensors: 33.6 MB
  unsigned short* Kl = Kh + NE;
  unsigned short* Vh = Kl + NE;
  unsigned short* Vl = Vh + NE;
  float* Out = (float*)d_out;

  prepass<<<3072, 256, 0, stream>>>(K, V, Kh, Kl, Vh, Vl);
  attn_main<<<NBH * (S_LEN / 64), 256, 0, stream>>>(Q, Kh, Kl, Vh, Vl, Out);
}

// Round 12
// 189.772 us; speedup vs baseline: 1.0377x; 1.0377x over previous
//
#include <hip/hip_runtime.h>
#include <hip/hip_bf16.h>

#define S_LEN 2048
#define D_DIM 64
#define NBH   32
#define NE    (NBH * S_LEN * D_DIM)   // 4,194,304 elements per tensor

typedef __attribute__((ext_vector_type(8))) short bf16x8;
typedef __attribute__((ext_vector_type(4))) short s16x4;
typedef __attribute__((ext_vector_type(2))) unsigned u32x2;
typedef __attribute__((ext_vector_type(4))) unsigned u32x4;
typedef __attribute__((ext_vector_type(4))) float f32x4;

__device__ __forceinline__ f32x4 mfma16(bf16x8 a, bf16x8 b, f32x4 c) {
  return __builtin_amdgcn_mfma_f32_16x16x32_bf16(a, b, c, 0, 0, 0);
}

__device__ __forceinline__ void gload16(const void* g, void* l) {
  __builtin_amdgcn_global_load_lds(
      (const __attribute__((address_space(1))) unsigned*)g,
      (__attribute__((address_space(3))) unsigned*)l, 16, 0, 0);
}

// packed bf16 convert (RNE): low16 = bf16(a), high16 = bf16(b)
__device__ __forceinline__ unsigned cvtpk(float a, float b) {
  unsigned r;
  asm("v_cvt_pk_bf16_f32 %0, %1, %2" : "=v"(r) : "v"(a), "v"(b));
  return r;
}
// hi/lo split of a pair via cvt_pk: returns {H, L} packed words
__device__ __forceinline__ u32x2 split2(float a, float b) {
  u32x2 r;
  r.x = cvtpk(a, b);
  const float fa = __builtin_bit_cast(float, r.x << 16);
  const float fb = __builtin_bit_cast(float, r.x & 0xffff0000u);
  r.y = cvtpk(a - fa, b - fb);
  return r;
}

// ---------- fused pre-pass: K -> Kh/Kl (same layout); V -> Vh/Vl transposed [bh][d][s]
__global__ __launch_bounds__(256) void prepass(const float* __restrict__ K,
                                               const float* __restrict__ V,
                                               unsigned short* __restrict__ Kh,
                                               unsigned short* __restrict__ Kl,
                                               unsigned short* __restrict__ Vh,
                                               unsigned short* __restrict__ Vl) {
  __shared__ float t[64][65];
  const int tid = threadIdx.x;
  if (blockIdx.x < 2048) {             // K convert: 8 floats / thread
    const int i = ((int)blockIdx.x * 256 + tid) * 8;
    float4 v0 = *(const float4*)(K + i);
    float4 v1 = *(const float4*)(K + i + 4);
    u32x4 H, L;
    u32x2 s;
    s = split2(v0.x, v0.y); H[0] = s.x; L[0] = s.y;
    s = split2(v0.z, v0.w); H[1] = s.x; L[1] = s.y;
    s = split2(v1.x, v1.y); H[2] = s.x; L[2] = s.y;
    s = split2(v1.z, v1.w); H[3] = s.x; L[3] = s.y;
    *(u32x4*)(Kh + i) = H;
    *(u32x4*)(Kl + i) = L;
  } else {                             // V transpose + convert
    const int bid = (int)blockIdx.x - 2048;
    const int bh  = bid >> 5;
    const int kv0 = (bid & 31) << 6;
#pragma unroll
    for (int pp = 0; pp < 4; ++pp) {
      const int r  = (tid >> 4) + pp * 16;
      const int c4 = (tid & 15) << 2;
      float4 v = *(const float4*)(V + ((size_t)bh * S_LEN + kv0 + r) * D_DIM + c4);
      t[r][c4] = v.x; t[r][c4 + 1] = v.y; t[r][c4 + 2] = v.z; t[r][c4 + 3] = v.w;
    }
    __syncthreads();
    const int d  = tid >> 2;
    const int k0 = (tid & 3) << 4;
    u32x4 H0, L0, H1, L1;
#pragma unroll
    for (int jj = 0; jj < 4; ++jj) {
      u32x2 s = split2(t[k0 + 2 * jj][d], t[k0 + 2 * jj + 1][d]);
      H0[jj] = s.x; L0[jj] = s.y;
    }
#pragma unroll
    for (int jj = 0; jj < 4; ++jj) {
      u32x2 s = split2(t[k0 + 8 + 2 * jj][d], t[k0 + 9 + 2 * jj][d]);
      H1[jj] = s.x; L1[jj] = s.y;
    }
    const size_t ob = ((size_t)bh * D_DIM + d) * S_LEN + kv0 + k0;
    *(u32x4*)(Vh + ob)     = H0;
    *(u32x4*)(Vh + ob + 8) = H1;
    *(u32x4*)(Vl + ob)     = L0;
    *(u32x4*)(Vl + ob + 8) = L1;
  }
}

// ---------- main: swapped-QK flash attention, prefetch dbuf, KBLK=32, P LDS bounce
__global__ __launch_bounds__(256) void attn_main(const float* __restrict__ Q,
                                                 const unsigned short* __restrict__ Kh,
                                                 const unsigned short* __restrict__ Kl,
                                                 const unsigned short* __restrict__ Vh,
                                                 const unsigned short* __restrict__ Vl,
                                                 float* __restrict__ Out) {
  __shared__ __align__(16) char smem[40960];
  unsigned short* sKh = (unsigned short*)smem;             // [2][32 kv][64 d] 8KB
  unsigned short* sKl = (unsigned short*)(smem + 8192);
  unsigned short* sVh = (unsigned short*)(smem + 16384);   // [2][64 d][32 kv] 8KB
  unsigned short* sVl = (unsigned short*)(smem + 24576);
  short*          sPh = (short*)(smem + 32768);            // per-wave 1KB
  short*          sPl = (short*)(smem + 36864);

  const int tid   = threadIdx.x;
  const int bh    = blockIdx.x & 31;          // same bh -> same XCD (32 % 8 == 0)
  const int qt    = 31 - (blockIdx.x >> 5);   // longest blocks first
  const int qbase = qt << 6;
  const int wave  = tid >> 6;
  const int lane  = tid & 63;
  const int c     = lane & 15;                // lane's q-row offset
  const int g     = lane >> 4;
  const int qw    = qbase + (wave << 4);

  const size_t bhO = (size_t)bh * (S_LEN * D_DIM);

  // Q as B-fragment: col = c = q-row, k = 8g+e = d. scale*log2e folded pre-split.
  const float SC = 0.125f * 1.44269504088896340736f;
  bf16x8 qh[2], ql[2];
#pragma unroll
  for (int ch = 0; ch < 2; ++ch) {
    const float* src = Q + bhO + (size_t)(qw + c) * D_DIM + ch * 32 + g * 8;
    float4 v0 = *(const float4*)src;
    float4 v1 = *(const float4*)(src + 4);
    float a[8] = {v0.x, v0.y, v0.z, v0.w, v1.x, v1.y, v1.z, v1.w};
    u32x4 H, L;
    u32x2 s;
    s = split2(a[0] * SC, a[1] * SC); H[0] = s.x; L[0] = s.y;
    s = split2(a[2] * SC, a[3] * SC); H[1] = s.x; L[1] = s.y;
    s = split2(a[4] * SC, a[5] * SC); H[2] = s.x; L[2] = s.y;
    s = split2(a[6] * SC, a[7] * SC); H[3] = s.x; L[3] = s.y;
    qh[ch] = __builtin_bit_cast(bf16x8, H);
    ql[ch] = __builtin_bit_cast(bf16x8, L);
  }

  f32x4 acc[4] = {{0.f,0.f,0.f,0.f},{0.f,0.f,0.f,0.f},{0.f,0.f,0.f,0.f},{0.f,0.f,0.f,0.f}};
  float m_r = -3.0e38f, l_r = 0.f;            // lane owns q-row qw+c

  const unsigned short* gKh = Kh + bhO;
  const unsigned short* gKl = Kl + bhO;
  const unsigned short* gVh = Vh + bhO;
  const unsigned short* gVl = Vl + bhO;

  const int rs   = tid >> 3;                         // K stage row (kv)
  const int kswz = ((tid & 7) ^ (rs & 7)) << 3;      // K source XOR (128B rows)
  const int vrow = tid >> 2;                         // V stage row (d)
  const int vcol = (((tid & 3) ^ ((tid >> 3) & 3)) << 3);  // V source XOR (64B rows)

  const int nIter = (qbase >> 5) + 2;

#define STAGE(itx, buf)                                                        \
  do {                                                                         \
    const int kv_ = (itx) << 5;                                                \
    gload16(gKh + (size_t)(kv_ + rs) * D_DIM + kswz,                           \
            sKh + ((buf) << 11) + (wave << 9));                                \
    gload16(gKl + (size_t)(kv_ + rs) * D_DIM + kswz,                           \
            sKl + ((buf) << 11) + (wave << 9));                                \
    gload16(gVh + (size_t)vrow * S_LEN + kv_ + vcol,                           \
            sVh + ((buf) << 11) + (wave << 9));                                \
    gload16(gVl + (size_t)vrow * S_LEN + kv_ + vcol,                           \
            sVl + ((buf) << 11) + (wave << 9));                                \
  } while (0)

  STAGE(0, 0);
  __syncthreads();
  int cur = 0;

  for (int it = 0; it < nIter; ++it) {
    if (it + 1 < nIter) STAGE(it + 1, cur ^ 1);   // prefetch: drains at END barrier
    const int kv0 = it << 5;

    if (kv0 <= qw + 15) {
      const int cb = cur << 11;
      // ---- QK^T swapped: S^T = mfma(A=K, B=Q). D: col=c=q, row=4g+r=kv-in-tile.
      f32x4 sj[2];
#pragma unroll
      for (int j = 0; j < 2; ++j) {
        const int row = (j << 4) + c;
        bf16x8 kfh[2], kfl[2];
#pragma unroll
        for (int ch = 0; ch < 2; ++ch) {
          const int p = ((ch << 2) + g) ^ (c & 7);
          kfh[ch] = *(const bf16x8*)&sKh[cb + (row << 6) + (p << 3)];
          kfl[ch] = *(const bf16x8*)&sKl[cb + (row << 6) + (p << 3)];
        }
        f32x4 sa = {0.f, 0.f, 0.f, 0.f};
        __builtin_amdgcn_s_setprio(1);
        sa = mfma16(kfh[0], qh[0], sa);
        sa = mfma16(kfh[1], qh[1], sa);
        sa = mfma16(kfh[0], ql[0], sa);
        sa = mfma16(kfh[1], ql[1], sa);
        sa = mfma16(kfl[0], qh[0], sa);
        sa = mfma16(kfl[1], qh[1], sa);
        __builtin_amdgcn_s_setprio(0);
        sj[j] = sa;
      }
      // causal mask: kv = kv0 + 16j + 4g + r vs q = qw + c
      if (kv0 + 31 > qw) {
#pragma unroll
        for (int j = 0; j < 2; ++j) {
          const int kvb = kv0 + (j << 4) + (g << 2);
#pragma unroll
          for (int r = 0; r < 4; ++r) {
            if (kvb + r > qw + c) sj[j][r] = -3.0e38f;
          }
        }
      }
      // ---- online softmax (lane-owned rows); defer-max: skip rescale if growth <= 8
      float pm = fmaxf(fmaxf(fmaxf(sj[0][0], sj[0][1]), fmaxf(sj[0][2], sj[0][3])),
                       fmaxf(fmaxf(sj[1][0], sj[1][1]), fmaxf(sj[1][2], sj[1][3])));
      pm = fmaxf(pm, __shfl_xor(pm, 16));
      pm = fmaxf(pm, __shfl_xor(pm, 32));
      if (!__all(pm <= m_r + 8.0f)) {       // p bounded by 2^8; scale cancels in l
        const float mn  = fmaxf(m_r, pm);
        const float fac = exp2f(m_r - mn);
        m_r = mn;
        l_r *= fac;
#pragma unroll
        for (int dt = 0; dt < 4; ++dt) acc[dt] *= fac;
      }
      float p[2][4];
      float ps = 0.f;
#pragma unroll
      for (int j = 0; j < 2; ++j)
#pragma unroll
        for (int r = 0; r < 4; ++r) {
          p[j][r] = exp2f(sj[j][r] - m_r);
          ps += p[j][r];
        }
      ps += __shfl_xor(ps, 16);
      ps += __shfl_xor(ps, 32);
      l_r += ps;

      // ---- pack P hi/lo, store as PV B-frag; 16B-block XOR swizzle ((c>>1)&3)
#pragma unroll
      for (int j = 0; j < 2; ++j) {
        u32x2 s0 = split2(p[j][0], p[j][1]);
        u32x2 s1 = split2(p[j][2], p[j][3]);
        const int blkp = ((j << 1) + (g >> 1)) ^ ((c >> 1) & 3);
        const int dw   = (wave << 8) + (c << 4) + (blkp << 2) + ((g & 1) << 1);
        u32x2 hw; hw[0] = s0.x; hw[1] = s1.x;
        u32x2 lw; lw[0] = s0.y; lw[1] = s1.y;
        *(s16x4*)&sPh[dw << 1] = __builtin_bit_cast(s16x4, hw);
        *(s16x4*)&sPl[dw << 1] = __builtin_bit_cast(s16x4, lw);
      }
      const int rdw = (wave << 8) + (c << 4) + ((g ^ ((c >> 1) & 3)) << 2);
      const bf16x8 pbh = *(const bf16x8*)&sPh[rdw << 1];
      const bf16x8 pbl = *(const bf16x8*)&sPl[rdw << 1];

      // ---- PV: O^T = mfma(A=V^T, B=P^T); V slot swizzle ((c>>1)&3)
      __builtin_amdgcn_s_setprio(1);
#pragma unroll
      for (int dt = 0; dt < 4; ++dt) {
        const int vb = cb + (((dt << 4) + c) << 5) + ((g ^ ((c >> 1) & 3)) << 3);
        const bf16x8 vfh = *(const bf16x8*)&sVh[vb];
        const bf16x8 vfl = *(const bf16x8*)&sVl[vb];
        acc[dt] = mfma16(vfh, pbh, acc[dt]);
        acc[dt] = mfma16(vfl, pbh, acc[dt]);
        acc[dt] = mfma16(vfh, pbl, acc[dt]);
      }
      __builtin_amdgcn_s_setprio(0);
    }
    __syncthreads();   // drains prefetch (vmcnt) + guards buffer swap
    cur ^= 1;
  }

  // ---- epilogue: O^T in regs -> LDS bounce (conflict-free float4) -> global
  const float inv = 1.0f / l_r;
  float (*ob)[68] = (float(*)[68])smem;       // 64x68 f32 = 17408 B
#pragma unroll
  for (int dt = 0; dt < 4; ++dt) {
    f32x4 o = acc[dt] * inv;
    *(f32x4*)&ob[(wave << 4) + c][(dt << 4) + (g << 2)] = o;
  }
  __syncthreads();
#pragma unroll
  for (int v = 0; v < 4; ++v) {
    const int row = (tid >> 4) + (v << 4);
    const int dc  = (tid & 15) << 2;
    float4 val = *(const float4*)&ob[row][dc];
    *(float4*)(Out + bhO + (size_t)(qbase + row) * D_DIM + dc) = val;
  }
}

extern "C" void kernel_launch(void* const* d_in, const int* in_sizes, int n_in,
                              void* d_out, int out_size, void* d_ws, size_t ws_size,
                              hipStream_t stream) {
  const float* Q = (const float*)d_in[0];
  const float* K = (const float*)d_in[1];
  const float* V = (const float*)d_in[2];
  // d_in[3] = mask: static causal tril, implemented analytically.

  unsigned short* Kh = (unsigned short*)d_ws;          // 4 bf16 tensors: 33.6 MB
  unsigned short* Kl = Kh + NE;
  unsigned short* Vh = Kl + NE;
  unsigned short* Vl = Vh + NE;
  float* Out = (float*)d_out;

  prepass<<<3072, 256, 0, stream>>>(K, V, Kh, Kl, Vh, Vl);
  attn_main<<<NBH * (S_LEN / 64), 256, 0, stream>>>(Q, Kh, Kl, Vh, Vl, Out);
}

// Round 13
// 179.737 us; speedup vs baseline: 1.0957x; 1.0558x over previous
//
#include <hip/hip_runtime.h>
#include <hip/hip_bf16.h>

#define S_LEN 2048
#define D_DIM 64
#define NBH   32
#define NE    (NBH * S_LEN * D_DIM)   // 4,194,304 elements per tensor

typedef __attribute__((ext_vector_type(8))) short bf16x8;
typedef __attribute__((ext_vector_type(4))) short s16x4;
typedef __attribute__((ext_vector_type(2))) unsigned u32x2;
typedef __attribute__((ext_vector_type(4))) unsigned u32x4;
typedef __attribute__((ext_vector_type(4))) float f32x4;

__device__ __forceinline__ f32x4 mfma16(bf16x8 a, bf16x8 b, f32x4 c) {
  return __builtin_amdgcn_mfma_f32_16x16x32_bf16(a, b, c, 0, 0, 0);
}

__device__ __forceinline__ void gload16(const void* g, void* l) {
  __builtin_amdgcn_global_load_lds(
      (const __attribute__((address_space(1))) unsigned*)g,
      (__attribute__((address_space(3))) unsigned*)l, 16, 0, 0);
}

// packed bf16 convert (RNE): low16 = bf16(a), high16 = bf16(b)
__device__ __forceinline__ unsigned cvtpk(float a, float b) {
  unsigned r;
  asm("v_cvt_pk_bf16_f32 %0, %1, %2" : "=v"(r) : "v"(a), "v"(b));
  return r;
}
// hi/lo split of a pair via cvt_pk: returns {H, L} packed words
__device__ __forceinline__ u32x2 split2(float a, float b) {
  u32x2 r;
  r.x = cvtpk(a, b);
  const float fa = __builtin_bit_cast(float, r.x << 16);
  const float fb = __builtin_bit_cast(float, r.x & 0xffff0000u);
  r.y = cvtpk(a - fa, b - fb);
  return r;
}

// ---------- fused pre-pass: K -> Kh/Kl (same layout); V -> Vh/Vl transposed [bh][d][s]
__global__ __launch_bounds__(256) void prepass(const float* __restrict__ K,
                                               const float* __restrict__ V,
                                               unsigned short* __restrict__ Kh,
                                               unsigned short* __restrict__ Kl,
                                               unsigned short* __restrict__ Vh,
                                               unsigned short* __restrict__ Vl) {
  __shared__ float t[64][65];
  const int tid = threadIdx.x;
  if (blockIdx.x < 2048) {             // K convert: 8 floats / thread
    const int i = ((int)blockIdx.x * 256 + tid) * 8;
    float4 v0 = *(const float4*)(K + i);
    float4 v1 = *(const float4*)(K + i + 4);
    u32x4 H, L;
    u32x2 s;
    s = split2(v0.x, v0.y); H[0] = s.x; L[0] = s.y;
    s = split2(v0.z, v0.w); H[1] = s.x; L[1] = s.y;
    s = split2(v1.x, v1.y); H[2] = s.x; L[2] = s.y;
    s = split2(v1.z, v1.w); H[3] = s.x; L[3] = s.y;
    *(u32x4*)(Kh + i) = H;
    *(u32x4*)(Kl + i) = L;
  } else {                             // V transpose + convert
    const int bid = (int)blockIdx.x - 2048;
    const int bh  = bid >> 5;
    const int kv0 = (bid & 31) << 6;
#pragma unroll
    for (int pp = 0; pp < 4; ++pp) {
      const int r  = (tid >> 4) + pp * 16;
      const int c4 = (tid & 15) << 2;
      float4 v = *(const float4*)(V + ((size_t)bh * S_LEN + kv0 + r) * D_DIM + c4);
      t[r][c4] = v.x; t[r][c4 + 1] = v.y; t[r][c4 + 2] = v.z; t[r][c4 + 3] = v.w;
    }
    __syncthreads();
    const int d  = tid >> 2;
    const int k0 = (tid & 3) << 4;
    u32x4 H0, L0, H1, L1;
#pragma unroll
    for (int jj = 0; jj < 4; ++jj) {
      u32x2 s = split2(t[k0 + 2 * jj][d], t[k0 + 2 * jj + 1][d]);
      H0[jj] = s.x; L0[jj] = s.y;
    }
#pragma unroll
    for (int jj = 0; jj < 4; ++jj) {
      u32x2 s = split2(t[k0 + 8 + 2 * jj][d], t[k0 + 9 + 2 * jj][d]);
      H1[jj] = s.x; L1[jj] = s.y;
    }
    const size_t ob = ((size_t)bh * D_DIM + d) * S_LEN + kv0 + k0;
    *(u32x4*)(Vh + ob)     = H0;
    *(u32x4*)(Vh + ob + 8) = H1;
    *(u32x4*)(Vl + ob)     = L0;
    *(u32x4*)(Vl + ob + 8) = L1;
  }
}

// ---------- main: swapped-QK flash attention, 8 waves = 2 KV-groups x 4 q-waves
__global__ __launch_bounds__(512) void attn_main(const float* __restrict__ Q,
                                                 const unsigned short* __restrict__ Kh,
                                                 const unsigned short* __restrict__ Kl,
                                                 const unsigned short* __restrict__ Vh,
                                                 const unsigned short* __restrict__ Vl,
                                                 float* __restrict__ Out) {
  // [grp][buf] K/V tiles (4KB each region) + per-wave P bounce
  __shared__ __align__(16) char smem[81920];               // 80KB -> 2 blocks/CU
  unsigned short* sKh = (unsigned short*)smem;             // [2][2][32][64] 16KB
  unsigned short* sKl = (unsigned short*)(smem + 16384);
  unsigned short* sVh = (unsigned short*)(smem + 32768);   // [2][2][64][32] 16KB
  unsigned short* sVl = (unsigned short*)(smem + 49152);
  short*          sPh = (short*)(smem + 65536);            // 8 waves x 1KB
  short*          sPl = (short*)(smem + 73728);

  const int tid   = threadIdx.x;
  const int bh    = blockIdx.x & 31;          // same bh -> same XCD (32 % 8 == 0)
  const int qt    = 31 - (blockIdx.x >> 5);   // longest blocks first
  const int qbase = qt << 6;
  const int wave  = tid >> 6;                 // 0..7
  const int grp   = wave >> 2;                // KV half: 0 = low, 1 = high
  const int wsub  = wave & 3;                 // q sub-tile within group
  const int lane  = tid & 63;
  const int c     = lane & 15;                // lane's q-row offset
  const int g     = lane >> 4;
  const int qw    = qbase + (wsub << 4);
  const int gtid  = tid & 255;                // thread index within group

  const size_t bhO = (size_t)bh * (S_LEN * D_DIM);

  // Q as B-fragment: col = c = q-row, k = 8g+e = d. scale*log2e folded pre-split.
  const float SC = 0.125f * 1.44269504088896340736f;
  bf16x8 qh[2], ql[2];
#pragma unroll
  for (int ch = 0; ch < 2; ++ch) {
    const float* src = Q + bhO + (size_t)(qw + c) * D_DIM + ch * 32 + g * 8;
    float4 v0 = *(const float4*)src;
    float4 v1 = *(const float4*)(src + 4);
    float a[8] = {v0.x, v0.y, v0.z, v0.w, v1.x, v1.y, v1.z, v1.w};
    u32x4 H, L;
    u32x2 s;
    s = split2(a[0] * SC, a[1] * SC); H[0] = s.x; L[0] = s.y;
    s = split2(a[2] * SC, a[3] * SC); H[1] = s.x; L[1] = s.y;
    s = split2(a[4] * SC, a[5] * SC); H[2] = s.x; L[2] = s.y;
    s = split2(a[6] * SC, a[7] * SC); H[3] = s.x; L[3] = s.y;
    qh[ch] = __builtin_bit_cast(bf16x8, H);
    ql[ch] = __builtin_bit_cast(bf16x8, L);
  }

  f32x4 acc[4] = {{0.f,0.f,0.f,0.f},{0.f,0.f,0.f,0.f},{0.f,0.f,0.f,0.f},{0.f,0.f,0.f,0.f}};
  float m_r = -3.0e38f, l_r = 0.f;            // lane owns q-row qw+c (group-local)

  const unsigned short* gKh = Kh + bhO;
  const unsigned short* gKl = Kl + bhO;
  const unsigned short* gVh = Vh + bhO;
  const unsigned short* gVl = Vl + bhO;

  const int rs   = gtid >> 3;                          // K stage row (kv)
  const int kswz = ((gtid & 7) ^ (rs & 7)) << 3;       // K source XOR (128B rows)
  const int vrow = gtid >> 2;                          // V stage row (d)
  const int vcol = (((gtid & 3) ^ ((gtid >> 3) & 3)) << 3);  // V source XOR (64B rows)

  const int nIterT = (qbase >> 5) + 2;        // total 32-kv tiles
  const int nHalf  = (nIterT + 1) >> 1;
  const int itStart = grp ? nHalf : 0;
  const int itEnd   = grp ? nIterT : nHalf;   // grp0: ceil(n/2), grp1: floor(n/2)

#define STAGE(itx, buf)                                                        \
  do {                                                                         \
    const int kv_ = (itx) << 5;                                                \
    const int rb_ = (((grp << 1) | (buf)) << 11) + (wsub << 9);                \
    gload16(gKh + (size_t)(kv_ + rs) * D_DIM + kswz, sKh + rb_);               \
    gload16(gKl + (size_t)(kv_ + rs) * D_DIM + kswz, sKl + rb_);               \
    gload16(gVh + (size_t)vrow * S_LEN + kv_ + vcol, sVh + rb_);               \
    gload16(gVl + (size_t)vrow * S_LEN + kv_ + vcol, sVl + rb_);               \
  } while (0)

  STAGE(itStart, 0);
  __syncthreads();

  for (int il = 0; il < nHalf; ++il) {
    const int myIt = itStart + il;
    const bool act = myIt < itEnd;            // wave-uniform
    if (act && myIt + 1 < itEnd) STAGE(myIt + 1, (il + 1) & 1);
    const int kv0 = myIt << 5;

    if (act && kv0 <= qw + 15) {
      const int kb = ((grp << 1) | (il & 1)) << 11;
      // ---- QK^T swapped: S^T = mfma(A=K, B=Q). D: col=c=q, row=4g+r=kv-in-tile.
      f32x4 sj[2];
#pragma unroll
      for (int j = 0; j < 2; ++j) {
        const int row = (j << 4) + c;
        bf16x8 kfh[2], kfl[2];
#pragma unroll
        for (int ch = 0; ch < 2; ++ch) {
          const int p = ((ch << 2) + g) ^ (c & 7);
          kfh[ch] = *(const bf16x8*)&sKh[kb + (row << 6) + (p << 3)];
          kfl[ch] = *(const bf16x8*)&sKl[kb + (row << 6) + (p << 3)];
        }
        f32x4 sa = {0.f, 0.f, 0.f, 0.f};
        sa = mfma16(kfh[0], qh[0], sa);
        sa = mfma16(kfh[1], qh[1], sa);
        sa = mfma16(kfh[0], ql[0], sa);
        sa = mfma16(kfh[1], ql[1], sa);
        sa = mfma16(kfl[0], qh[0], sa);
        sa = mfma16(kfl[1], qh[1], sa);
        sj[j] = sa;
      }
      // causal mask: kv = kv0 + 16j + 4g + r vs q = qw + c
      if (kv0 + 31 > qw) {
#pragma unroll
        for (int j = 0; j < 2; ++j) {
          const int kvb = kv0 + (j << 4) + (g << 2);
#pragma unroll
          for (int r = 0; r < 4; ++r) {
            if (kvb + r > qw + c) sj[j][r] = -3.0e38f;
          }
        }
      }
      // ---- online softmax (lane-owned rows); defer-max THR=8
      float pm = fmaxf(fmaxf(fmaxf(sj[0][0], sj[0][1]), fmaxf(sj[0][2], sj[0][3])),
                       fmaxf(fmaxf(sj[1][0], sj[1][1]), fmaxf(sj[1][2], sj[1][3])));
      pm = fmaxf(pm, __shfl_xor(pm, 16));
      pm = fmaxf(pm, __shfl_xor(pm, 32));
      if (!__all(pm <= m_r + 8.0f)) {         // p bounded by 2^8; scale cancels in l
        const float mn  = fmaxf(m_r, pm);
        const float fac = exp2f(m_r - mn);
        m_r = mn;
        l_r *= fac;
#pragma unroll
        for (int dt = 0; dt < 4; ++dt) acc[dt] *= fac;
      }
      float p[2][4];
      float ps = 0.f;
#pragma unroll
      for (int j = 0; j < 2; ++j)
#pragma unroll
        for (int r = 0; r < 4; ++r) {
          p[j][r] = exp2f(sj[j][r] - m_r);
          ps += p[j][r];
        }
      ps += __shfl_xor(ps, 16);
      ps += __shfl_xor(ps, 32);
      l_r += ps;

      // ---- pack P hi/lo, store as PV B-frag; 16B-block XOR swizzle ((c>>1)&3)
#pragma unroll
      for (int j = 0; j < 2; ++j) {
        u32x2 s0 = split2(p[j][0], p[j][1]);
        u32x2 s1 = split2(p[j][2], p[j][3]);
        const int blkp = ((j << 1) + (g >> 1)) ^ ((c >> 1) & 3);
        const int dw   = (wave << 8) + (c << 4) + (blkp << 2) + ((g & 1) << 1);
        u32x2 hw; hw[0] = s0.x; hw[1] = s1.x;
        u32x2 lw; lw[0] = s0.y; lw[1] = s1.y;
        *(s16x4*)&sPh[dw << 1] = __builtin_bit_cast(s16x4, hw);
        *(s16x4*)&sPl[dw << 1] = __builtin_bit_cast(s16x4, lw);
      }
      const int rdw = (wave << 8) + (c << 4) + ((g ^ ((c >> 1) & 3)) << 2);
      const bf16x8 pbh = *(const bf16x8*)&sPh[rdw << 1];
      const bf16x8 pbl = *(const bf16x8*)&sPl[rdw << 1];

      // ---- PV: O^T = mfma(A=V^T, B=P^T); V slot swizzle ((c>>1)&3)
#pragma unroll
      for (int dt = 0; dt < 4; ++dt) {
        const int vb = kb + (((dt << 4) + c) << 5) + ((g ^ ((c >> 1) & 3)) << 3);
        const bf16x8 vfh = *(const bf16x8*)&sVh[vb];
        const bf16x8 vfl = *(const bf16x8*)&sVl[vb];
        acc[dt] = mfma16(vfh, pbh, acc[dt]);
        acc[dt] = mfma16(vfl, pbh, acc[dt]);
        acc[dt] = mfma16(vfh, pbl, acc[dt]);
      }
    }
    __syncthreads();   // drains prefetch + guards buffer swap (all 8 waves)
  }

  // ---- cross-group combine (grp0 partial + grp1 partial) + store
  float* ax = (float*)smem + wsub * 1040;     // per-wsub 16 q x 65 f32 (padded)
  float* mf = (float*)(smem + 65536);         // reuses P area (done)
  float* lf = mf + 64;
  if (grp == 0) {
#pragma unroll
    for (int dt = 0; dt < 4; ++dt)
#pragma unroll
      for (int r = 0; r < 4; ++r)
        ax[c * 65 + (dt << 4) + (g << 2) + r] = acc[dt][r];
    if (g == 0) { mf[(wsub << 4) + c] = m_r; lf[(wsub << 4) + c] = l_r; }
  }
  __syncthreads();
  float (*ob)[68] = (float(*)[68])(smem + 32768);   // reuses V area (done)
  if (grp == 1) {
    const float m0 = mf[(wsub << 4) + c], l0 = lf[(wsub << 4) + c];
    const float M  = fmaxf(m0, m_r);
    const float f0 = exp2f(m0 - M), f1 = exp2f(m_r - M);
    const float inv = 1.0f / (f0 * l0 + f1 * l_r);
#pragma unroll
    for (int dt = 0; dt < 4; ++dt) {
      f32x4 o;
#pragma unroll
      for (int r = 0; r < 4; ++r)
        o[r] = (f0 * ax[c * 65 + (dt << 4) + (g << 2) + r] + f1 * acc[dt][r]) * inv;
      *(f32x4*)&ob[(wsub << 4) + c][(dt << 4) + (g << 2)] = o;
    }
  }
  __syncthreads();
  if (grp == 1) {                              // coalesced store, 256 threads
    const int t2 = tid & 255;
#pragma unroll
    for (int v = 0; v < 4; ++v) {
      const int row = (t2 >> 4) + (v << 4);
      const int dc  = (t2 & 15) << 2;
      *(float4*)(Out + bhO + (size_t)(qbase + row) * D_DIM + dc) =
          *(const float4*)&ob[row][dc];
    }
  }
}

extern "C" void kernel_launch(void* const* d_in, const int* in_sizes, int n_in,
                              void* d_out, int out_size, void* d_ws, size_t ws_size,
                              hipStream_t stream) {
  const float* Q = (const float*)d_in[0];
  const float* K = (const float*)d_in[1];
  const float* V = (const float*)d_in[2];
  // d_in[3] = mask: static causal tril, implemented analytically.

  unsigned short* Kh = (unsigned short*)d_ws;          // 4 bf16 tensors: 33.6 MB
  unsigned short* Kl = Kh + NE;
  unsigned short* Vh = Kl + NE;
  unsigned short* Vl = Vh + NE;
  float* Out = (float*)d_out;

  prepass<<<3072, 256, 0, stream>>>(K, V, Kh, Kl, Vh, Vl);
  attn_main<<<NBH * (S_LEN / 64), 512, 0, stream>>>(Q, Kh, Kl, Vh, Vl, Out);
}